// Round 5
// baseline (129.621 us; speedup 1.0000x reference)
//
#include <hip/hip_runtime.h>
#include <hip/hip_bf16.h>

// Problem constants (B=32, N=256, K=20, channels 3->64->128->256, fc 256->128->40)
#define B_ 32
#define N_ 256
#define K_ 20
#define C1 64
#define C2 128
#define C3 256
#define F1 128
#define F2 40
#define NEG_INF (-3.402823466e38f)

// wave-uniform broadcast from register via readlane (SGPR result, no LDS pipe)
#define RL(v, l) __int_as_float(__builtin_amdgcn_readlane(__float_as_int(v), (l)))

// ---------------------------------------------------------------------------
// NODE 1: three independent block families (unchanged from R3):
//   blocks [0,512):     per-point MLP, 16 pts/block.
//   blocks [512,2560):  per-point top-20, one wave per point; radix-select.
//   blocks [2560,2576): fc1 weight transpose fc1T[n][j] = fc1w[j][n].
// ---------------------------------------------------------------------------
__global__ __launch_bounds__(256) void k_front(const float* __restrict__ x,
    const float* __restrict__ w1, const float* __restrict__ s1, const float* __restrict__ b1,
    const float* __restrict__ w2, const float* __restrict__ s2, const float* __restrict__ b2,
    const float* __restrict__ w3, const float* __restrict__ s3, const float* __restrict__ b3,
    const float* __restrict__ fc1w,
    int* __restrict__ idx, float* __restrict__ P, float* __restrict__ fc1T) {

    __shared__ float smem[3136];        // mlp only: xs 64 | y1 1024 | y2 2048
    const int blk  = blockIdx.x;
    const int t    = threadIdx.x;
    const int lane = t & 63;
    const int wv   = t >> 6;

    if (blk < 512) {
        // ================== per-point MLP, 16 points/block ==================
        float* xs = smem;               // 48 used
        float* y1 = smem + 64;          // [c1][p] 64x16
        float* y2 = smem + 1088;        // [c2][p] 128x16
        const int pbase = blk * 16;
        const int og = t >> 2;          // oc-group 0..63 (4 adjacent lanes share)
        const int p0 = (t & 3) * 4;     // pt-quad

        if (t < 48) xs[t] = x[(size_t)pbase * 3 + t];
        __syncthreads();

        // ---- layer 1: 64 x 3; thread = (oc=lane, pt-quad=wv) ----
        {
            const int oc = lane;
            const float wa = w1[oc * 3 + 0], wb = w1[oc * 3 + 1], wc = w1[oc * 3 + 2];
            const float sc = s1[oc], sh = b1[oc];
            const int q0 = wv * 4;
            float4 v;
            #pragma unroll
            for (int p = 0; p < 4; ++p) {
                const int pp = q0 + p;
                float vv = wa * xs[pp * 3 + 0] + wb * xs[pp * 3 + 1] + wc * xs[pp * 3 + 2];
                (&v.x)[p] = fmaxf(vv * sc + sh, 0.0f);
            }
            *(float4*)&y1[oc * 16 + q0] = v;
        }
        __syncthreads();

        // ---- layer 2: 128oc x 64k; thread = (2-oc group og, pt-quad) ----
        {
            const int oc0 = og * 2;
            float acc[2][4] = {};
            for (int k = 0; k < C1; k += 4) {
                float4 a[4];
                #pragma unroll
                for (int kk = 0; kk < 4; ++kk)
                    a[kk] = *(const float4*)&y1[(k + kk) * 16 + p0];
                const float4 wA = *(const float4*)(w2 + (size_t)oc0 * C1 + k);       // 4-lane dup
                const float4 wB = *(const float4*)(w2 + (size_t)(oc0 + 1) * C1 + k); // merges
                #pragma unroll
                for (int kk = 0; kk < 4; ++kk) {
                    #pragma unroll
                    for (int p = 0; p < 4; ++p) {
                        acc[0][p] += (&wA.x)[kk] * (&a[kk].x)[p];
                        acc[1][p] += (&wB.x)[kk] * (&a[kk].x)[p];
                    }
                }
            }
            const float sc0 = s2[oc0], sh0 = b2[oc0];
            const float sc1 = s2[oc0 + 1], sh1 = b2[oc0 + 1];
            float4 v0, v1;
            #pragma unroll
            for (int p = 0; p < 4; ++p) {
                (&v0.x)[p] = fmaxf(acc[0][p] * sc0 + sh0, 0.0f);
                (&v1.x)[p] = fmaxf(acc[1][p] * sc1 + sh1, 0.0f);
            }
            *(float4*)&y2[oc0 * 16 + p0]       = v0;
            *(float4*)&y2[(oc0 + 1) * 16 + p0] = v1;
        }
        __syncthreads();

        // ---- layer 3: 256oc x 128k; thread = (4-oc group og, pt-quad) ----
        {
            const int oc0 = og * 4;
            float acc[4][4] = {};
            for (int k = 0; k < C2; k += 4) {
                float4 a[4];
                #pragma unroll
                for (int kk = 0; kk < 4; ++kk)
                    a[kk] = *(const float4*)&y2[(k + kk) * 16 + p0];
                float4 w[4];
                #pragma unroll
                for (int o = 0; o < 4; ++o)
                    w[o] = *(const float4*)(w3 + (size_t)(oc0 + o) * C2 + k);        // 4-lane dup
                #pragma unroll
                for (int o = 0; o < 4; ++o) {
                    #pragma unroll
                    for (int kk = 0; kk < 4; ++kk) {
                        const float wvv = (&w[o].x)[kk];
                        #pragma unroll
                        for (int p = 0; p < 4; ++p)
                            acc[o][p] += wvv * (&a[kk].x)[p];
                    }
                }
            }
            const float4 sc = *(const float4*)&s3[oc0];
            const float4 sh = *(const float4*)&b3[oc0];
            #pragma unroll
            for (int p = 0; p < 4; ++p) {
                float4 v;
                #pragma unroll
                for (int o = 0; o < 4; ++o)
                    (&v.x)[o] = fmaxf(acc[o][p] * (&sc.x)[o] + (&sh.x)[o], 0.0f);
                *(float4*)&P[(size_t)(pbase + p0 + p) * C3 + oc0] = v;
            }
        }

    } else if (blk < 2560) {
        // ================== top-20, one wave per point, LDS-free ==================
        const int tb = blk - 512;
        const int b  = tb >> 6;
        const int n  = ((tb & 63) << 2) | wv;
        const int bn = (b << 8) | n;
        const float* xb = x + (size_t)b * N_ * 3;

        const float nx = xb[n * 3 + 0], ny = xb[n * 3 + 1], nz = xb[n * 3 + 2];
        const float xxn = nx * nx + ny * ny + nz * nz;

        unsigned k0, k1, k2, k3;
        {
            unsigned kk[4];
            #pragma unroll
            for (int i = 0; i < 4; ++i) {
                const int m = lane + (i << 6);
                const float cx = xb[m * 3 + 0], cy = xb[m * 3 + 1], cz = xb[m * 3 + 2];
                const float xxm = cx * cx + cy * cy + cz * cz;
                const float v = 2.0f * (nx * cx + ny * cy + nz * cz) - xxn - xxm;
                const unsigned u = __float_as_uint(v);
                kk[i] = (u & 0x80000000u) ? ~u : (u | 0x80000000u);   // monotone
            }
            k0 = kk[0]; k1 = kk[1]; k2 = kk[2]; k3 = kk[3];
        }
        // Self point: v == +0.0 exactly -> key 0x80000000, strict max; bit 31
        // of T is provably 0, so the bit-31 step is skipped.

        unsigned prefix = 0u;
        #pragma unroll
        for (int bit = 30; bit >= 0; --bit) {
            const unsigned cand = prefix | (1u << bit);
            const int c = __popcll(__ballot(k0 >= cand))
                        + __popcll(__ballot(k1 >= cand))
                        + __popcll(__ballot(k2 >= cand))
                        + __popcll(__ballot(k3 >= cand));
            if (c >= K_) prefix = cand;
        }
        const unsigned T = prefix;          // count(>=T) >= 20, count(>T) < 20

        int* op = idx + (size_t)bn * K_;
        const unsigned long long lt = (1ull << lane) - 1ull;

        const unsigned long long G0 = __ballot(k0 > T);
        const unsigned long long G1 = __ballot(k1 > T);
        const unsigned long long G2 = __ballot(k2 > T);
        const unsigned long long G3 = __ballot(k3 > T);
        const int n0 = __popcll(G0), n1 = __popcll(G1), n2 = __popcll(G2), n3 = __popcll(G3);
        const int g = n0 + n1 + n2 + n3;
        if (k0 > T) op[          __popcll(G0 & lt)] = lane;
        if (k1 > T) op[n0      + __popcll(G1 & lt)] = 64  | lane;
        if (k2 > T) op[n0 + n1 + __popcll(G2 & lt)] = 128 | lane;
        if (k3 > T) op[n0 + n1 + n2 + __popcll(G3 & lt)] = 192 | lane;

        const int e = K_ - g;               // >= 1 by maximality of T
        const unsigned long long E0 = __ballot(k0 == T);
        const unsigned long long E1 = __ballot(k1 == T);
        const unsigned long long E2 = __ballot(k2 == T);
        const unsigned long long E3 = __ballot(k3 == T);
        const int m0 = __popcll(E0), m1 = __popcll(E1), m2 = __popcll(E2);
        if (k0 == T) { const int p = __popcll(E0 & lt);                 if (p < e) op[g + p] = lane; }
        if (k1 == T) { const int p = m0 + __popcll(E1 & lt);            if (p < e) op[g + p] = 64  | lane; }
        if (k2 == T) { const int p = m0 + m1 + __popcll(E2 & lt);       if (p < e) op[g + p] = 128 | lane; }
        if (k3 == T) { const int p = m0 + m1 + m2 + __popcll(E3 & lt);  if (p < e) op[g + p] = 192 | lane; }

    } else {
        // ================== fc1 weight transpose ==================
        const int g = (blk - 2560) * 256 + t;   // 0..4095
        #pragma unroll
        for (int i = 0; i < 8; ++i) {           // 32768 elems
            const int e = g + i * 4096;
            const int j = e >> 8, nn = e & 255;
            fc1T[nn * F1 + j] = fc1w[e];
        }
    }
}

// ---------------------------------------------------------------------------
// NODE 2: FUSED gather-max + fc1(relu) + fc2.
// R5 = R4 (readlane replaces broadcast LDS reads) with the divergence bug
// fixed: R4's stage-C glT slice loads were sunk INTO the m<F2 branch by the
// compiler (their only uses were there), so lanes 40-63 never loaded and
// readlane(g, j>=40) returned garbage. Now stage C computes unconditionally
// on all 64 lanes (clamped w2l row for lanes >= F2, results discarded) and
// the loads additionally carry an asm keepalive before any divergence.
// ---------------------------------------------------------------------------
#define HT_S  20                        // Ht row stride (words), %4==0 for b128
#define GLT_S 20                        // glT row stride (words)

__device__ __forceinline__ void btile(const float* __restrict__ fc1T, float* ftile,
                                      int nt, int t, int lane, const float4 a,
                                      float acc0[4], float acc1[4]) {
    // cooperative coalesced tile load: rows nt*64 .. nt*64+63 of fc1T
    const float4* src = (const float4*)(fc1T + (size_t)nt * 64 * F1);
    float4* dst = (float4*)ftile;
    #pragma unroll
    for (int i = 0; i < 8; ++i)
        dst[t + i * 256] = src[t + i * 256];
    __syncthreads();
    #pragma unroll 4
    for (int nn = 0; nn < 64; ++nn) {
        const float2 w = *(const float2*)&ftile[nn * F1 + lane * 2]; // per-lane b64
        const float s0 = RL(a.x, nn);   // wave-uniform a-values: readlane,
        const float s1 = RL(a.y, nn);   // no LDS traffic
        const float s2 = RL(a.z, nn);
        const float s3 = RL(a.w, nn);
        acc0[0] += w.x * s0;  acc0[1] += w.x * s1;
        acc0[2] += w.x * s2;  acc0[3] += w.x * s3;
        acc1[0] += w.y * s0;  acc1[1] += w.y * s1;
        acc1[2] += w.y * s2;  acc1[3] += w.y * s3;
    }
    __syncthreads();                    // ftile dead before next overwrite
}

__global__ __launch_bounds__(256) void k_gfc(const float* __restrict__ P,
                                             const int* __restrict__ idx,
                                             const float* __restrict__ fc1T,
                                             const float* __restrict__ fc1b,
                                             const float* __restrict__ fc2w,
                                             const float* __restrict__ fc2b,
                                             float* __restrict__ out) {
    const int b    = blockIdx.x >> 4;
    const int ch0  = (blockIdx.x & 15) * 16;
    const int t    = threadIdx.x;
    const int lane = t & 63;
    const int wv   = t >> 6;

    __shared__ float smem[15872];       // 63.5 KB
    float* Ht    = smem;                // [n][HT_S] 256x20 (20 KB), dead after B
    float* ftile = smem + 5120;         // [64][128] fc1T tile (32 KB), dead after B
    float* glT   = smem + 13312;        // [j][GLT_S] 128x20 (10 KB)
    float* w2l   = smem;                // [m][j] 40x129, aliases Ht/ftile post-B

    // ---- stage A: gather-max into Ht ----
    {
        const int q  = t & 3;           // ch-quad
        const int nl = t >> 2;          // n within quarter-pass
        const float* Pq = P + (size_t)b * N_ * C3 + ch0 + q * 4;
        #pragma unroll
        for (int r = 0; r < 4; ++r) {
            const int n = r * 64 + nl;
            const int4* ib4 = (const int4*)(idx + ((size_t)((b << 8) | n)) * K_);
            float4 m = make_float4(NEG_INF, NEG_INF, NEG_INF, NEG_INF);
            #pragma unroll
            for (int jv = 0; jv < 5; ++jv) {          // 20 ids as 5 x int4
                const int4 id4 = ib4[jv];
                #pragma unroll
                for (int jj = 0; jj < 4; ++jj) {      // j ascending, order kept
                    const int id = (&id4.x)[jj];
                    const float4 p = *(const float4*)(Pq + (size_t)id * C3);
                    m.x = fmaxf(m.x, p.x);
                    m.y = fmaxf(m.y, p.y);
                    m.z = fmaxf(m.z, p.z);
                    m.w = fmaxf(m.w, p.w);
                }
            }
            *(float4*)&Ht[n * HT_S + q * 4] = m;
        }
    }
    __syncthreads();

    // ---- stage B: fc1 + relu -> glT[j][ci]; w LDS-tiled, a via readlane ----
    {
        const int c0 = wv * 4;          // wave's ch-quad
        // one-time slice load: lane holds Ht[r*64+lane][c0..c0+3], r=0..3
        const float4 a0 = *(const float4*)&Ht[(0 * 64 + lane) * HT_S + c0];
        const float4 a1 = *(const float4*)&Ht[(1 * 64 + lane) * HT_S + c0];
        const float4 a2 = *(const float4*)&Ht[(2 * 64 + lane) * HT_S + c0];
        const float4 a3 = *(const float4*)&Ht[(3 * 64 + lane) * HT_S + c0];
        float acc0[4] = {}, acc1[4] = {};
        btile(fc1T, ftile, 0, t, lane, a0, acc0, acc1);
        btile(fc1T, ftile, 1, t, lane, a1, acc0, acc1);
        btile(fc1T, ftile, 2, t, lane, a2, acc0, acc1);
        btile(fc1T, ftile, 3, t, lane, a3, acc0, acc1);

        const float bb0 = fc1b[lane * 2], bb1 = fc1b[lane * 2 + 1];
        float4 va, vb;
        #pragma unroll
        for (int c = 0; c < 4; ++c) {
            (&va.x)[c] = fmaxf(acc0[c] + bb0, 0.0f);
            (&vb.x)[c] = fmaxf(acc1[c] + bb1, 0.0f);
        }
        // rows j = 2*lane, 2*lane+1; this wave owns columns c0..c0+3
        *(float4*)&glT[(lane * 2)     * GLT_S + c0] = va;
        *(float4*)&glT[(lane * 2 + 1) * GLT_S + c0] = vb;
    }
    // Ht/ftile dead (trailing barrier of last tile passed) -> fill w2l.
    for (int e = t; e < F2 * F1; e += 256)
        w2l[(e >> 7) * 129 + (e & 127)] = fc2w[e];
    __syncthreads();

    // ---- stage C: fc2 -> out. wave = ci-quad, lane = m; g via readlane.
    //      ALL 64 lanes compute (loads must not sink into a divergent
    //      region: readlane reads lanes 40-63's registers). Only the final
    //      stores are guarded by m < F2.
    {
        const int m   = lane;
        const int cig = wv;             // ci = cig*4 .. cig*4+3
        const float4 g0 = *(const float4*)&glT[(lane)      * GLT_S + cig * 4];
        const float4 g1 = *(const float4*)&glT[(64 + lane) * GLT_S + cig * 4];
        // pin the loads before any divergence (rule-#17 keepalive)
        asm volatile("" :: "v"(g0.x), "v"(g0.y), "v"(g0.z), "v"(g0.w),
                           "v"(g1.x), "v"(g1.y), "v"(g1.z), "v"(g1.w));
        const int mr = m < F2 ? m : 0;  // lanes >= F2 compute a discarded dot
        float a0 = 0.f, a1 = 0.f, a2 = 0.f, a3 = 0.f;
        const float* wr = w2l + mr * 129;       // per-lane b32, ~2-way banks
        #pragma unroll 4
        for (int j = 0; j < 64; ++j) {          // j 0..63 ascending
            const float w = wr[j];
            a0 += w * RL(g0.x, j);
            a1 += w * RL(g0.y, j);
            a2 += w * RL(g0.z, j);
            a3 += w * RL(g0.w, j);
        }
        #pragma unroll 4
        for (int j = 0; j < 64; ++j) {          // j 64..127 ascending
            const float w = wr[64 + j];
            a0 += w * RL(g1.x, j);
            a1 += w * RL(g1.y, j);
            a2 += w * RL(g1.z, j);
            a3 += w * RL(g1.w, j);
        }
        if (m < F2) {
            const float bb = fc2b[m];
            const size_t rb = (size_t)(b * C3 + ch0 + cig * 4) * F2 + m;
            out[rb]          = a0 + bb;
            out[rb + F2]     = a1 + bb;
            out[rb + 2 * F2] = a2 + bb;
            out[rb + 3 * F2] = a3 + bb;
        }
    }
}

// ---------------------------------------------------------------------------
extern "C" void kernel_launch(void* const* d_in, const int* in_sizes, int n_in,
                              void* d_out, int out_size, void* d_ws, size_t ws_size,
                              hipStream_t stream) {
    const float* x    = (const float*)d_in[0];
    const float* w1   = (const float*)d_in[1];
    const float* s1   = (const float*)d_in[2];
    const float* t1   = (const float*)d_in[3];
    const float* w2   = (const float*)d_in[4];
    const float* s2   = (const float*)d_in[5];
    const float* t2   = (const float*)d_in[6];
    const float* w3   = (const float*)d_in[7];
    const float* s3   = (const float*)d_in[8];
    const float* t3   = (const float*)d_in[9];
    const float* fc1w = (const float*)d_in[10];
    const float* fc1b = (const float*)d_in[11];
    const float* fc2w = (const float*)d_in[12];
    const float* fc2b = (const float*)d_in[13];
    float* out = (float*)d_out;

    // Workspace layout (all fully overwritten every call):
    char* ws = (char*)d_ws;
    int*   idx  = (int*)ws;                                  // 655,360 B
    float* P    = (float*)(ws + (size_t)B_ * N_ * K_ * 4);   // 8 MB
    float* fc1T = P + (size_t)B_ * N_ * C3;                  // 131,072 B

    k_front<<<2576, 256, 0, stream>>>(x, w1, s1, t1, w2, s2, t2, w3, s3, t3,
                                      fc1w, idx, P, fc1T);
    k_gfc<<<B_ * 16, 256, 0, stream>>>(P, idx, fc1T, fc1b, fc2w, fc2b, out);
}

// Round 7
// 126.500 us; speedup vs baseline: 1.0247x; 1.0247x over previous
//
#include <hip/hip_runtime.h>
#include <hip/hip_bf16.h>

// Problem constants (B=32, N=256, K=20, channels 3->64->128->256, fc 256->128->40)
#define B_ 32
#define N_ 256
#define K_ 20
#define C1 64
#define C2 128
#define C3 256
#define F1 128
#define F2 40
#define NEG_INF (-3.402823466e38f)

// DPP helpers: sum over each 16-lane row (all 16 lanes end with the row sum).
// dpp_ctrl must be an ICE at the builtin call -> template parameter.
template <int CTRL>
__device__ __forceinline__ float dpp_mov(float v) {
    return __int_as_float(__builtin_amdgcn_update_dpp(0, __float_as_int(v), CTRL, 0xF, 0xF, true));
}
__device__ __forceinline__ float row16_sum(float v) {
    v += dpp_mov<0xB1>(v);   // quad_perm [1,0,3,2]  (lane ^ 1)
    v += dpp_mov<0x4E>(v);   // quad_perm [2,3,0,1]  (lane ^ 2)
    v += dpp_mov<0x141>(v);  // row_half_mirror      (pairs quads within 8)
    v += dpp_mov<0x140>(v);  // row_mirror           (pairs 8s within 16)
    return v;
}

// ---------------------------------------------------------------------------
// NODE 1: three independent block families (unchanged since R3):
//   blocks [0,512):     per-point MLP, 16 pts/block.
//   blocks [512,2560):  per-point top-20, one wave per point; radix-select.
//   blocks [2560,2576): fc1 weight transpose fc1T[n][j] = fc1w[j][n].
// ---------------------------------------------------------------------------
__global__ __launch_bounds__(256) void k_front(const float* __restrict__ x,
    const float* __restrict__ w1, const float* __restrict__ s1, const float* __restrict__ b1,
    const float* __restrict__ w2, const float* __restrict__ s2, const float* __restrict__ b2,
    const float* __restrict__ w3, const float* __restrict__ s3, const float* __restrict__ b3,
    const float* __restrict__ fc1w,
    int* __restrict__ idx, float* __restrict__ P, float* __restrict__ fc1T) {

    __shared__ float smem[3136];        // mlp only: xs 64 | y1 1024 | y2 2048
    const int blk  = blockIdx.x;
    const int t    = threadIdx.x;
    const int lane = t & 63;
    const int wv   = t >> 6;

    if (blk < 512) {
        // ================== per-point MLP, 16 points/block ==================
        float* xs = smem;               // 48 used
        float* y1 = smem + 64;          // [c1][p] 64x16
        float* y2 = smem + 1088;        // [c2][p] 128x16
        const int pbase = blk * 16;
        const int og = t >> 2;          // oc-group 0..63 (4 adjacent lanes share)
        const int p0 = (t & 3) * 4;     // pt-quad

        if (t < 48) xs[t] = x[(size_t)pbase * 3 + t];
        __syncthreads();

        // ---- layer 1: 64 x 3; thread = (oc=lane, pt-quad=wv) ----
        {
            const int oc = lane;
            const float wa = w1[oc * 3 + 0], wb = w1[oc * 3 + 1], wc = w1[oc * 3 + 2];
            const float sc = s1[oc], sh = b1[oc];
            const int q0 = wv * 4;
            float4 v;
            #pragma unroll
            for (int p = 0; p < 4; ++p) {
                const int pp = q0 + p;
                float vv = wa * xs[pp * 3 + 0] + wb * xs[pp * 3 + 1] + wc * xs[pp * 3 + 2];
                (&v.x)[p] = fmaxf(vv * sc + sh, 0.0f);
            }
            *(float4*)&y1[oc * 16 + q0] = v;
        }
        __syncthreads();

        // ---- layer 2: 128oc x 64k; thread = (2-oc group og, pt-quad) ----
        {
            const int oc0 = og * 2;
            float acc[2][4] = {};
            for (int k = 0; k < C1; k += 4) {
                float4 a[4];
                #pragma unroll
                for (int kk = 0; kk < 4; ++kk)
                    a[kk] = *(const float4*)&y1[(k + kk) * 16 + p0];
                const float4 wA = *(const float4*)(w2 + (size_t)oc0 * C1 + k);       // 4-lane dup
                const float4 wB = *(const float4*)(w2 + (size_t)(oc0 + 1) * C1 + k); // merges
                #pragma unroll
                for (int kk = 0; kk < 4; ++kk) {
                    #pragma unroll
                    for (int p = 0; p < 4; ++p) {
                        acc[0][p] += (&wA.x)[kk] * (&a[kk].x)[p];
                        acc[1][p] += (&wB.x)[kk] * (&a[kk].x)[p];
                    }
                }
            }
            const float sc0 = s2[oc0], sh0 = b2[oc0];
            const float sc1 = s2[oc0 + 1], sh1 = b2[oc0 + 1];
            float4 v0, v1;
            #pragma unroll
            for (int p = 0; p < 4; ++p) {
                (&v0.x)[p] = fmaxf(acc[0][p] * sc0 + sh0, 0.0f);
                (&v1.x)[p] = fmaxf(acc[1][p] * sc1 + sh1, 0.0f);
            }
            *(float4*)&y2[oc0 * 16 + p0]       = v0;
            *(float4*)&y2[(oc0 + 1) * 16 + p0] = v1;
        }
        __syncthreads();

        // ---- layer 3: 256oc x 128k; thread = (4-oc group og, pt-quad) ----
        {
            const int oc0 = og * 4;
            float acc[4][4] = {};
            for (int k = 0; k < C2; k += 4) {
                float4 a[4];
                #pragma unroll
                for (int kk = 0; kk < 4; ++kk)
                    a[kk] = *(const float4*)&y2[(k + kk) * 16 + p0];
                float4 w[4];
                #pragma unroll
                for (int o = 0; o < 4; ++o)
                    w[o] = *(const float4*)(w3 + (size_t)(oc0 + o) * C2 + k);        // 4-lane dup
                #pragma unroll
                for (int o = 0; o < 4; ++o) {
                    #pragma unroll
                    for (int kk = 0; kk < 4; ++kk) {
                        const float wvv = (&w[o].x)[kk];
                        #pragma unroll
                        for (int p = 0; p < 4; ++p)
                            acc[o][p] += wvv * (&a[kk].x)[p];
                    }
                }
            }
            const float4 sc = *(const float4*)&s3[oc0];
            const float4 sh = *(const float4*)&b3[oc0];
            #pragma unroll
            for (int p = 0; p < 4; ++p) {
                float4 v;
                #pragma unroll
                for (int o = 0; o < 4; ++o)
                    (&v.x)[o] = fmaxf(acc[o][p] * (&sc.x)[o] + (&sh.x)[o], 0.0f);
                *(float4*)&P[(size_t)(pbase + p0 + p) * C3 + oc0] = v;
            }
        }

    } else if (blk < 2560) {
        // ================== top-20, one wave per point, LDS-free ==================
        const int tb = blk - 512;
        const int b  = tb >> 6;
        const int n  = ((tb & 63) << 2) | wv;
        const int bn = (b << 8) | n;
        const float* xb = x + (size_t)b * N_ * 3;

        const float nx = xb[n * 3 + 0], ny = xb[n * 3 + 1], nz = xb[n * 3 + 2];
        const float xxn = nx * nx + ny * ny + nz * nz;

        unsigned k0, k1, k2, k3;
        {
            unsigned kk[4];
            #pragma unroll
            for (int i = 0; i < 4; ++i) {
                const int m = lane + (i << 6);
                const float cx = xb[m * 3 + 0], cy = xb[m * 3 + 1], cz = xb[m * 3 + 2];
                const float xxm = cx * cx + cy * cy + cz * cz;
                const float v = 2.0f * (nx * cx + ny * cy + nz * cz) - xxn - xxm;
                const unsigned u = __float_as_uint(v);
                kk[i] = (u & 0x80000000u) ? ~u : (u | 0x80000000u);   // monotone
            }
            k0 = kk[0]; k1 = kk[1]; k2 = kk[2]; k3 = kk[3];
        }
        // Self point: v == +0.0 exactly -> key 0x80000000, strict max; bit 31
        // of T is provably 0, so the bit-31 step is skipped.

        unsigned prefix = 0u;
        #pragma unroll
        for (int bit = 30; bit >= 0; --bit) {
            const unsigned cand = prefix | (1u << bit);
            const int c = __popcll(__ballot(k0 >= cand))
                        + __popcll(__ballot(k1 >= cand))
                        + __popcll(__ballot(k2 >= cand))
                        + __popcll(__ballot(k3 >= cand));
            if (c >= K_) prefix = cand;
        }
        const unsigned T = prefix;          // count(>=T) >= 20, count(>T) < 20

        int* op = idx + (size_t)bn * K_;
        const unsigned long long lt = (1ull << lane) - 1ull;

        const unsigned long long G0 = __ballot(k0 > T);
        const unsigned long long G1 = __ballot(k1 > T);
        const unsigned long long G2 = __ballot(k2 > T);
        const unsigned long long G3 = __ballot(k3 > T);
        const int n0 = __popcll(G0), n1 = __popcll(G1), n2 = __popcll(G2), n3 = __popcll(G3);
        const int g = n0 + n1 + n2 + n3;
        if (k0 > T) op[          __popcll(G0 & lt)] = lane;
        if (k1 > T) op[n0      + __popcll(G1 & lt)] = 64  | lane;
        if (k2 > T) op[n0 + n1 + __popcll(G2 & lt)] = 128 | lane;
        if (k3 > T) op[n0 + n1 + n2 + __popcll(G3 & lt)] = 192 | lane;

        const int e = K_ - g;               // >= 1 by maximality of T
        const unsigned long long E0 = __ballot(k0 == T);
        const unsigned long long E1 = __ballot(k1 == T);
        const unsigned long long E2 = __ballot(k2 == T);
        const unsigned long long E3 = __ballot(k3 == T);
        const int m0 = __popcll(E0), m1 = __popcll(E1), m2 = __popcll(E2);
        if (k0 == T) { const int p = __popcll(E0 & lt);                 if (p < e) op[g + p] = lane; }
        if (k1 == T) { const int p = m0 + __popcll(E1 & lt);            if (p < e) op[g + p] = 64  | lane; }
        if (k2 == T) { const int p = m0 + m1 + __popcll(E2 & lt);       if (p < e) op[g + p] = 128 | lane; }
        if (k3 == T) { const int p = m0 + m1 + m2 + __popcll(E3 & lt);  if (p < e) op[g + p] = 192 | lane; }

    } else {
        // ================== fc1 weight transpose ==================
        const int g = (blk - 2560) * 256 + t;   // 0..4095
        #pragma unroll
        for (int i = 0; i < 8; ++i) {           // 32768 elems
            const int e = g + i * 4096;
            const int j = e >> 8, nn = e & 255;
            fc1T[nn * F1 + j] = fc1w[e];
        }
    }
}

// ---------------------------------------------------------------------------
// NODE 2: FUSED gather-max + fc1(relu) + fc2.
// R7 = R6 with the DPP ctrl made a template parameter (compile fix).
// Stage B is R3's exact form (ftile staging + Ht b128 broadcast). Stage C:
// fc1 outputs stay IN REGISTERS (lane l holds Y[2l,2l+1][c-quad]); per m,
// per-lane partial (8 FMA) reduced over j by a 4-step DPP tree within
// 16-lane rows (pure VALU, no LDS broadcast); 4 row-partials stored via one
// 4-lane ds_write_b128; tiny final pass sums them + bias. glT gone. fp32 sum
// order over j changes (tree) -- allowed: harness threshold 5.19e-2 in bf16.
// ---------------------------------------------------------------------------
__global__ __launch_bounds__(256) void k_gfc(const float* __restrict__ P,
                                             const int* __restrict__ idx,
                                             const float* __restrict__ fc1T,
                                             const float* __restrict__ fc1b,
                                             const float* __restrict__ fc2w,
                                             const float* __restrict__ fc2b,
                                             float* __restrict__ out) {
    const int b    = blockIdx.x >> 4;
    const int ch0  = (blockIdx.x & 15) * 16;
    const int t    = threadIdx.x;
    const int lane = t & 63;
    const int wv   = t >> 6;

    __shared__ float smem[15488];       // 62 KB
    float* Ht    = smem;                // [n][16] 256x16 (16 KB), dead after B
    float* ftile = smem + 4096;         // [64][128] fc1T tile (32 KB), dead after B
    float* part  = smem + 12288;        // [wv][m][row][c] 4 x 40 x 20 words
    float* w2s   = smem;                // staggered fc2w pairs, aliases Ht post-B

    // ---- stage A: gather-max into Ht ----
    {
        const int q  = t & 3;           // ch-quad
        const int nl = t >> 2;          // n within quarter-pass
        const float* Pq = P + (size_t)b * N_ * C3 + ch0 + q * 4;
        #pragma unroll
        for (int r = 0; r < 4; ++r) {
            const int n = r * 64 + nl;
            const int4* ib4 = (const int4*)(idx + ((size_t)((b << 8) | n)) * K_);
            float4 m = make_float4(NEG_INF, NEG_INF, NEG_INF, NEG_INF);
            #pragma unroll
            for (int jv = 0; jv < 5; ++jv) {          // 20 ids as 5 x int4
                const int4 id4 = ib4[jv];
                #pragma unroll
                for (int jj = 0; jj < 4; ++jj) {
                    const int id = (&id4.x)[jj];
                    const float4 p = *(const float4*)(Pq + (size_t)id * C3);
                    m.x = fmaxf(m.x, p.x);
                    m.y = fmaxf(m.y, p.y);
                    m.z = fmaxf(m.z, p.z);
                    m.w = fmaxf(m.w, p.w);
                }
            }
            *(float4*)&Ht[n * 16 + q * 4] = m;
        }
    }
    __syncthreads();

    // ---- stage B: fc1 -> registers (R3 exact: ftile staging, Ht broadcast) ----
    const int c0 = wv * 4;              // wave's ch-quad
    float va[4], vb[4];
    {
        float acc0[4] = {}, acc1[4] = {};
        for (int nt = 0; nt < 4; ++nt) {
            // cooperative coalesced tile load: rows nt*64 .. nt*64+63
            {
                const float4* src = (const float4*)(fc1T + (size_t)nt * 64 * F1);
                float4* dst = (float4*)ftile;
                #pragma unroll
                for (int i = 0; i < 8; ++i)
                    dst[t + i * 256] = src[t + i * 256];
            }
            __syncthreads();
            #pragma unroll 4
            for (int nn = 0; nn < 64; ++nn) {
                const int n = nt * 64 + nn;
                const float2 w = *(const float2*)&ftile[nn * F1 + lane * 2]; // 2-way banks
                const float4 a = *(const float4*)&Ht[n * 16 + c0];           // broadcast
                #pragma unroll
                for (int c = 0; c < 4; ++c) {
                    acc0[c] += w.x * (&a.x)[c];
                    acc1[c] += w.y * (&a.x)[c];
                }
            }
            __syncthreads();            // ftile/Ht dead after last pass
        }
        const float bb0 = fc1b[lane * 2], bb1 = fc1b[lane * 2 + 1];
        #pragma unroll
        for (int c = 0; c < 4; ++c) {
            va[c] = fmaxf(acc0[c] + bb0, 0.0f);     // Y[2*lane][c0+c]
            vb[c] = fmaxf(acc1[c] + bb1, 0.0f);     // Y[2*lane+1][c0+c]
        }
    }

    // ---- w2s fill: staggered per-lane pair pack {w2[m][2l], w2[m][2l+1]} at
    //      word m*134 + 2l + 2*(l>>4)  (8B aligned; 2-way banks on read) ----
    for (int e = t; e < F2 * 64; e += 256) {
        const int m = e >> 6, l = e & 63;
        const int o = m * 134 + 2 * l + 2 * (l >> 4);
        w2s[o]     = fc2w[m * F1 + 2 * l];
        w2s[o + 1] = fc2w[m * F1 + 2 * l + 1];
    }
    __syncthreads();

    // ---- stage C: fc2 via in-register DPP reduction over j ----
    {
        const int woff = 2 * lane + 2 * (lane >> 4);
        const int prow = lane >> 4;         // 16-lane row = j-block of 32
        float* pb = part + wv * 800;        // this wave's partial buffer
        const bool writer = (lane & 15) == 0;
        for (int m = 0; m < F2; ++m) {
            const float2 wp = *(const float2*)&w2s[m * 134 + woff];
            float p0 = wp.x * va[0] + wp.y * vb[0];
            float p1 = wp.x * va[1] + wp.y * vb[1];
            float p2 = wp.x * va[2] + wp.y * vb[2];
            float p3 = wp.x * va[3] + wp.y * vb[3];
            p0 = row16_sum(p0);             // sum over this row's 32 j's
            p1 = row16_sum(p1);
            p2 = row16_sum(p2);
            p3 = row16_sum(p3);
            if (writer) {                   // lanes 0,16,32,48: one per row
                float4 pv = make_float4(p0, p1, p2, p3);
                *(float4*)&pb[m * 20 + prow * 4] = pv;
            }
        }
    }
    __syncthreads();

    // ---- final: sum 4 row-partials + bias, store ----
    {
        const float* pb = part + wv * 800;
        const int bch = b * C3 + ch0 + wv * 4;
        for (int o = lane; o < 160; o += 64) {
            const int m = o % 40, cc = o / 40;
            const float* pp = pb + m * 20 + cc;
            const float v = pp[0] + pp[4] + pp[8] + pp[12] + fc2b[m];
            out[(size_t)(bch + cc) * F2 + m] = v;
        }
    }
}

// ---------------------------------------------------------------------------
extern "C" void kernel_launch(void* const* d_in, const int* in_sizes, int n_in,
                              void* d_out, int out_size, void* d_ws, size_t ws_size,
                              hipStream_t stream) {
    const float* x    = (const float*)d_in[0];
    const float* w1   = (const float*)d_in[1];
    const float* s1   = (const float*)d_in[2];
    const float* t1   = (const float*)d_in[3];
    const float* w2   = (const float*)d_in[4];
    const float* s2   = (const float*)d_in[5];
    const float* t2   = (const float*)d_in[6];
    const float* w3   = (const float*)d_in[7];
    const float* s3   = (const float*)d_in[8];
    const float* t3   = (const float*)d_in[9];
    const float* fc1w = (const float*)d_in[10];
    const float* fc1b = (const float*)d_in[11];
    const float* fc2w = (const float*)d_in[12];
    const float* fc2b = (const float*)d_in[13];
    float* out = (float*)d_out;

    // Workspace layout (all fully overwritten every call):
    char* ws = (char*)d_ws;
    int*   idx  = (int*)ws;                                  // 655,360 B
    float* P    = (float*)(ws + (size_t)B_ * N_ * K_ * 4);   // 8 MB
    float* fc1T = P + (size_t)B_ * N_ * C3;                  // 131,072 B

    k_front<<<2576, 256, 0, stream>>>(x, w1, s1, t1, w2, s2, t2, w3, s3, t3,
                                      fc1w, idx, P, fc1T);
    k_gfc<<<B_ * 16, 256, 0, stream>>>(P, idx, fc1T, fc1b, fc2w, fc2b, out);
}

// Round 8
// 123.600 us; speedup vs baseline: 1.0487x; 1.0235x over previous
//
#include <hip/hip_runtime.h>
#include <hip/hip_bf16.h>

// Problem constants (B=32, N=256, K=20, channels 3->64->128->256, fc 256->128->40)
#define B_ 32
#define N_ 256
#define K_ 20
#define C1 64
#define C2 128
#define C3 256
#define F1 128
#define F2 40
#define NEG_INF (-3.402823466e38f)

// ---------------------------------------------------------------------------
// NODE 1: three independent block families:
//   blocks [0,512):     per-point MLP, 16 pts/block.
//   blocks [512,2560):  per-point top-20, one wave per point; radix-select
//                       for the 20th-largest monotone key (exact stable
//                       tie-break; output order irrelevant to gather-max).
//   blocks [2560,2576): fc1 weight transpose fc1T[n][j] = fc1w[j][n].
// ---------------------------------------------------------------------------
__global__ __launch_bounds__(256) void k_front(const float* __restrict__ x,
    const float* __restrict__ w1, const float* __restrict__ s1, const float* __restrict__ b1,
    const float* __restrict__ w2, const float* __restrict__ s2, const float* __restrict__ b2,
    const float* __restrict__ w3, const float* __restrict__ s3, const float* __restrict__ b3,
    const float* __restrict__ fc1w,
    int* __restrict__ idx, float* __restrict__ P, float* __restrict__ fc1T) {

    __shared__ float smem[3136];        // mlp only: xs 64 | y1 1024 | y2 2048
    const int blk  = blockIdx.x;
    const int t    = threadIdx.x;
    const int lane = t & 63;
    const int wv   = t >> 6;

    if (blk < 512) {
        // ================== per-point MLP, 16 points/block ==================
        float* xs = smem;               // 48 used
        float* y1 = smem + 64;          // [c1][p] 64x16
        float* y2 = smem + 1088;        // [c2][p] 128x16
        const int pbase = blk * 16;
        const int og = t >> 2;          // oc-group 0..63 (4 adjacent lanes share)
        const int p0 = (t & 3) * 4;     // pt-quad

        if (t < 48) xs[t] = x[(size_t)pbase * 3 + t];
        __syncthreads();

        // ---- layer 1: 64 x 3; thread = (oc=lane, pt-quad=wv) ----
        {
            const int oc = lane;
            const float wa = w1[oc * 3 + 0], wb = w1[oc * 3 + 1], wc = w1[oc * 3 + 2];
            const float sc = s1[oc], sh = b1[oc];
            const int q0 = wv * 4;
            float4 v;
            #pragma unroll
            for (int p = 0; p < 4; ++p) {
                const int pp = q0 + p;
                float vv = wa * xs[pp * 3 + 0] + wb * xs[pp * 3 + 1] + wc * xs[pp * 3 + 2];
                (&v.x)[p] = fmaxf(vv * sc + sh, 0.0f);
            }
            *(float4*)&y1[oc * 16 + q0] = v;
        }
        __syncthreads();

        // ---- layer 2: 128oc x 64k; thread = (2-oc group og, pt-quad) ----
        {
            const int oc0 = og * 2;
            float acc[2][4] = {};
            for (int k = 0; k < C1; k += 4) {
                float4 a[4];
                #pragma unroll
                for (int kk = 0; kk < 4; ++kk)
                    a[kk] = *(const float4*)&y1[(k + kk) * 16 + p0];
                const float4 wA = *(const float4*)(w2 + (size_t)oc0 * C1 + k);       // 4-lane dup
                const float4 wB = *(const float4*)(w2 + (size_t)(oc0 + 1) * C1 + k); // merges
                #pragma unroll
                for (int kk = 0; kk < 4; ++kk) {
                    #pragma unroll
                    for (int p = 0; p < 4; ++p) {
                        acc[0][p] += (&wA.x)[kk] * (&a[kk].x)[p];
                        acc[1][p] += (&wB.x)[kk] * (&a[kk].x)[p];
                    }
                }
            }
            const float sc0 = s2[oc0], sh0 = b2[oc0];
            const float sc1 = s2[oc0 + 1], sh1 = b2[oc0 + 1];
            float4 v0, v1;
            #pragma unroll
            for (int p = 0; p < 4; ++p) {
                (&v0.x)[p] = fmaxf(acc[0][p] * sc0 + sh0, 0.0f);
                (&v1.x)[p] = fmaxf(acc[1][p] * sc1 + sh1, 0.0f);
            }
            *(float4*)&y2[oc0 * 16 + p0]       = v0;
            *(float4*)&y2[(oc0 + 1) * 16 + p0] = v1;
        }
        __syncthreads();

        // ---- layer 3: 256oc x 128k; thread = (4-oc group og, pt-quad) ----
        {
            const int oc0 = og * 4;
            float acc[4][4] = {};
            for (int k = 0; k < C2; k += 4) {
                float4 a[4];
                #pragma unroll
                for (int kk = 0; kk < 4; ++kk)
                    a[kk] = *(const float4*)&y2[(k + kk) * 16 + p0];
                float4 w[4];
                #pragma unroll
                for (int o = 0; o < 4; ++o)
                    w[o] = *(const float4*)(w3 + (size_t)(oc0 + o) * C2 + k);        // 4-lane dup
                #pragma unroll
                for (int o = 0; o < 4; ++o) {
                    #pragma unroll
                    for (int kk = 0; kk < 4; ++kk) {
                        const float wvv = (&w[o].x)[kk];
                        #pragma unroll
                        for (int p = 0; p < 4; ++p)
                            acc[o][p] += wvv * (&a[kk].x)[p];
                    }
                }
            }
            const float4 sc = *(const float4*)&s3[oc0];
            const float4 sh = *(const float4*)&b3[oc0];
            #pragma unroll
            for (int p = 0; p < 4; ++p) {
                float4 v;
                #pragma unroll
                for (int o = 0; o < 4; ++o)
                    (&v.x)[o] = fmaxf(acc[o][p] * (&sc.x)[o] + (&sh.x)[o], 0.0f);
                *(float4*)&P[(size_t)(pbase + p0 + p) * C3 + oc0] = v;
            }
        }

    } else if (blk < 2560) {
        // ================== top-20, one wave per point, LDS-free ==================
        const int tb = blk - 512;
        const int b  = tb >> 6;
        const int n  = ((tb & 63) << 2) | wv;
        const int bn = (b << 8) | n;
        const float* xb = x + (size_t)b * N_ * 3;

        const float nx = xb[n * 3 + 0], ny = xb[n * 3 + 1], nz = xb[n * 3 + 2];
        const float xxn = nx * nx + ny * ny + nz * nz;

        unsigned k0, k1, k2, k3;
        {
            unsigned kk[4];
            #pragma unroll
            for (int i = 0; i < 4; ++i) {
                const int m = lane + (i << 6);
                const float cx = xb[m * 3 + 0], cy = xb[m * 3 + 1], cz = xb[m * 3 + 2];
                const float xxm = cx * cx + cy * cy + cz * cz;
                const float v = 2.0f * (nx * cx + ny * cy + nz * cz) - xxn - xxm;
                const unsigned u = __float_as_uint(v);
                kk[i] = (u & 0x80000000u) ? ~u : (u | 0x80000000u);   // monotone
            }
            k0 = kk[0]; k1 = kk[1]; k2 = kk[2]; k3 = kk[3];
        }
        // Self point: v == +0.0 exactly -> key 0x80000000, strict max; bit 31
        // of T is provably 0, so the bit-31 step is skipped.

        unsigned prefix = 0u;
        #pragma unroll
        for (int bit = 30; bit >= 0; --bit) {
            const unsigned cand = prefix | (1u << bit);
            const int c = __popcll(__ballot(k0 >= cand))
                        + __popcll(__ballot(k1 >= cand))
                        + __popcll(__ballot(k2 >= cand))
                        + __popcll(__ballot(k3 >= cand));
            if (c >= K_) prefix = cand;
        }
        const unsigned T = prefix;          // count(>=T) >= 20, count(>T) < 20

        int* op = idx + (size_t)bn * K_;
        const unsigned long long lt = (1ull << lane) - 1ull;

        const unsigned long long G0 = __ballot(k0 > T);
        const unsigned long long G1 = __ballot(k1 > T);
        const unsigned long long G2 = __ballot(k2 > T);
        const unsigned long long G3 = __ballot(k3 > T);
        const int n0 = __popcll(G0), n1 = __popcll(G1), n2 = __popcll(G2), n3 = __popcll(G3);
        const int g = n0 + n1 + n2 + n3;
        if (k0 > T) op[          __popcll(G0 & lt)] = lane;
        if (k1 > T) op[n0      + __popcll(G1 & lt)] = 64  | lane;
        if (k2 > T) op[n0 + n1 + __popcll(G2 & lt)] = 128 | lane;
        if (k3 > T) op[n0 + n1 + n2 + __popcll(G3 & lt)] = 192 | lane;

        const int e = K_ - g;               // >= 1 by maximality of T
        const unsigned long long E0 = __ballot(k0 == T);
        const unsigned long long E1 = __ballot(k1 == T);
        const unsigned long long E2 = __ballot(k2 == T);
        const unsigned long long E3 = __ballot(k3 == T);
        const int m0 = __popcll(E0), m1 = __popcll(E1), m2 = __popcll(E2);
        if (k0 == T) { const int p = __popcll(E0 & lt);                 if (p < e) op[g + p] = lane; }
        if (k1 == T) { const int p = m0 + __popcll(E1 & lt);            if (p < e) op[g + p] = 64  | lane; }
        if (k2 == T) { const int p = m0 + m1 + __popcll(E2 & lt);       if (p < e) op[g + p] = 128 | lane; }
        if (k3 == T) { const int p = m0 + m1 + m2 + __popcll(E3 & lt);  if (p < e) op[g + p] = 192 | lane; }

    } else {
        // ================== fc1 weight transpose ==================
        const int g = (blk - 2560) * 256 + t;   // 0..4095
        #pragma unroll
        for (int i = 0; i < 8; ++i) {           // 32768 elems
            const int e = g + i * 4096;
            const int j = e >> 8, nn = e & 255;
            fc1T[nn * F1 + j] = fc1w[e];
        }
    }
}

// ---------------------------------------------------------------------------
// NODE 2: FUSED gather-max + fc1(relu) + fc2.
// R8 = exact revert to R3 (best measured: 123.35 us). Post-R7 knowledge:
// the wave-uniform broadcast ds_reads here are HW-broadcast (cheap, overlap
// with VALU); replacing them with readlane (R5) or DPP trees (R7) moved work
// onto the VALU pipe and regressed. Stage B stages fc1T in LDS tiles once
// per block (the R3 win: kills 4x redundant per-wave global streaming).
// ---------------------------------------------------------------------------
#define GLT_S 20                        // glT row stride (words), %4==0 for b128
__global__ __launch_bounds__(256) void k_gfc(const float* __restrict__ P,
                                             const int* __restrict__ idx,
                                             const float* __restrict__ fc1T,
                                             const float* __restrict__ fc1b,
                                             const float* __restrict__ fc2w,
                                             const float* __restrict__ fc2b,
                                             float* __restrict__ out) {
    const int b    = blockIdx.x >> 4;
    const int ch0  = (blockIdx.x & 15) * 16;
    const int t    = threadIdx.x;
    const int lane = t & 63;

    __shared__ float smem[14848];       // 59.4 KB
    float* Ht    = smem;                // [n][ci] 256x16 (16 KB), dead after B
    float* ftile = smem + 4096;         // [64][128] fc1T tile (32 KB), dead after B
    float* glT   = smem + 12288;        // [j][ci] 128x20 (10.25 KB)
    float* w2l   = smem;                // [m][j] 40x129, aliases Ht/ftile post-B

    // ---- stage A: gather-max into Ht ----
    {
        const int q  = t & 3;           // ch-quad
        const int nl = t >> 2;          // n within quarter-pass
        const float* Pq = P + (size_t)b * N_ * C3 + ch0 + q * 4;
        #pragma unroll
        for (int r = 0; r < 4; ++r) {
            const int n = r * 64 + nl;
            const int* ib = idx + ((size_t)((b << 8) | n)) * K_;
            float4 m = make_float4(NEG_INF, NEG_INF, NEG_INF, NEG_INF);
            #pragma unroll
            for (int j = 0; j < K_; ++j) {
                const int id = ib[j];
                const float4 p = *(const float4*)(Pq + (size_t)id * C3);
                m.x = fmaxf(m.x, p.x);
                m.y = fmaxf(m.y, p.y);
                m.z = fmaxf(m.z, p.z);
                m.w = fmaxf(m.w, p.w);
            }
            *(float4*)&Ht[n * 16 + q * 4] = m;
        }
    }
    __syncthreads();

    // ---- stage B: fc1 + relu -> glT[j][ci]; fc1T LDS-tiled ----
    {
        const int c0 = (t >> 6) * 4;    // wave's ch-quad
        float acc[2][4] = {};
        for (int nt = 0; nt < 4; ++nt) {
            // cooperative coalesced tile load: rows nt*64 .. nt*64+63
            {
                const float4* src = (const float4*)(fc1T + (size_t)nt * 64 * F1);
                float4* dst = (float4*)ftile;
                #pragma unroll
                for (int i = 0; i < 8; ++i)
                    dst[t + i * 256] = src[t + i * 256];
            }
            __syncthreads();
            #pragma unroll 4
            for (int nn = 0; nn < 64; ++nn) {
                const int n = nt * 64 + nn;
                const float2 w = *(const float2*)&ftile[nn * F1 + lane * 2]; // 2-way banks
                const float4 a = *(const float4*)&Ht[n * 16 + c0];           // broadcast
                #pragma unroll
                for (int c = 0; c < 4; ++c) {
                    acc[0][c] += w.x * (&a.x)[c];
                    acc[1][c] += w.y * (&a.x)[c];
                }
            }
            __syncthreads();            // ftile dead before next overwrite
        }
        const float bb0 = fc1b[lane * 2], bb1 = fc1b[lane * 2 + 1];
        float4 va, vb;
        #pragma unroll
        for (int c = 0; c < 4; ++c) {
            (&va.x)[c] = fmaxf(acc[0][c] + bb0, 0.0f);
            (&vb.x)[c] = fmaxf(acc[1][c] + bb1, 0.0f);
        }
        // rows j = 2*lane, 2*lane+1; this wave owns columns c0..c0+3
        *(float4*)&glT[(lane * 2)     * GLT_S + c0] = va;
        *(float4*)&glT[(lane * 2 + 1) * GLT_S + c0] = vb;
    }
    // Ht/ftile are dead (trailing barrier of tile loop passed) -> fill w2l.
    for (int e = t; e < F2 * F1; e += 256)
        w2l[(e >> 7) * 129 + (e & 127)] = fc2w[e];
    __syncthreads();

    // ---- stage C: fc2 -> out. wave = ci-quad (cig), lane = m (40 of 64) ----
    {
        const int m   = t & 63;
        const int cig = t >> 6;         // 0..3 -> ci = cig*4 .. cig*4+3
        if (m < F2) {
            float a0 = 0.f, a1 = 0.f, a2 = 0.f, a3 = 0.f;
            const float* wr = w2l + m * 129;        // per-lane row, ~2-way banks
            const float* gp = glT + cig * 4;        // wave-uniform -> broadcast
            #pragma unroll 4
            for (int j = 0; j < F1; ++j) {
                const float w = wr[j];
                const float4 gv = *(const float4*)(gp + j * GLT_S);
                a0 += w * gv.x;
                a1 += w * gv.y;
                a2 += w * gv.z;
                a3 += w * gv.w;
            }
            const float bb = fc2b[m];
            const size_t rb = (size_t)(b * C3 + ch0 + cig * 4) * F2 + m;
            out[rb]          = a0 + bb;
            out[rb + F2]     = a1 + bb;
            out[rb + 2 * F2] = a2 + bb;
            out[rb + 3 * F2] = a3 + bb;
        }
    }
}

// ---------------------------------------------------------------------------
extern "C" void kernel_launch(void* const* d_in, const int* in_sizes, int n_in,
                              void* d_out, int out_size, void* d_ws, size_t ws_size,
                              hipStream_t stream) {
    const float* x    = (const float*)d_in[0];
    const float* w1   = (const float*)d_in[1];
    const float* s1   = (const float*)d_in[2];
    const float* t1   = (const float*)d_in[3];
    const float* w2   = (const float*)d_in[4];
    const float* s2   = (const float*)d_in[5];
    const float* t2   = (const float*)d_in[6];
    const float* w3   = (const float*)d_in[7];
    const float* s3   = (const float*)d_in[8];
    const float* t3   = (const float*)d_in[9];
    const float* fc1w = (const float*)d_in[10];
    const float* fc1b = (const float*)d_in[11];
    const float* fc2w = (const float*)d_in[12];
    const float* fc2b = (const float*)d_in[13];
    float* out = (float*)d_out;

    // Workspace layout (all fully overwritten every call):
    char* ws = (char*)d_ws;
    int*   idx  = (int*)ws;                                  // 655,360 B
    float* P    = (float*)(ws + (size_t)B_ * N_ * K_ * 4);   // 8 MB
    float* fc1T = P + (size_t)B_ * N_ * C3;                  // 131,072 B

    k_front<<<2576, 256, 0, stream>>>(x, w1, s1, t1, w2, s2, t2, w3, s3, t3,
                                      fc1w, idx, P, fc1T);
    k_gfc<<<B_ * 16, 256, 0, stream>>>(P, idx, fc1T, fc1b, fc2w, fc2b, out);
}